// Round 1
// baseline (139.533 us; speedup 1.0000x reference)
//
#include <hip/hip_runtime.h>
#include <math.h>

#define BB  8
#define HH  512
#define WW  512
#define HID 32
#define KK  25

#define TS 16          // output tile (16x16 threads)
#define GT 18          // guidance tile with 1-px halo (conv3x3 pad=1)
#define FT 20          // flow tile with 2-px halo (unfold K=5 pad=2)

__global__ __launch_bounds__(256)
void temporal_refine_kernel(const float* __restrict__ v0,   // [B,2,H,W] flow
                            const float* __restrict__ v2,   // [B,2,H,W]
                            const float* __restrict__ w1,   // [32,3,3,3]
                            const float* __restrict__ b1,   // [32]
                            const float* __restrict__ w2,   // [50,32]
                            const float* __restrict__ b2,   // [50]
                            float* __restrict__ out)        // [B,2,H,W]
{
    __shared__ float g_lds[3][GT][GT + 1];  // guidance: fb0, fb1, w
    __shared__ float f_lds[2][FT][FT];      // flow patch source

    const int bx0 = blockIdx.x * TS;
    const int by0 = blockIdx.y * TS;
    const int b   = blockIdx.z;
    const int tx  = threadIdx.x, ty = threadIdx.y;
    const int tid = ty * TS + tx;

    const float* v0b = v0 + (size_t)b * 2 * HH * WW;
    const float* v2b = v2 + (size_t)b * 2 * HH * WW;

    // ---- guidance tile with halo 1 (zero outside image == conv zero-pad) ----
    for (int i = tid; i < GT * GT; i += 256) {
        const int ly = i / GT, lx = i - ly * GT;
        const int y = by0 - 1 + ly, x = bx0 - 1 + lx;
        float fb0 = 0.f, fb1 = 0.f, wv = 0.f;
        if (y >= 0 && y < HH && x >= 0 && x < WW) {
            const float f0 = v0b[y * WW + x];
            const float f1 = v0b[HH * WW + y * WW + x];
            // grid-sample coords, align_corners=True (mirrors reference fp ops)
            const float sgx = (-1.0f + x * (2.0f / (WW - 1))) + f0 * (2.0f / WW);
            const float sgy = (-1.0f + y * (2.0f / (HH - 1))) + f1 * (2.0f / HH);
            const float ixf = (sgx + 1.0f) * (0.5f * (WW - 1));
            const float iyf = (sgy + 1.0f) * (0.5f * (HH - 1));
            const float x0f = floorf(ixf), y0f = floorf(iyf);
            const int   x0  = (int)x0f,   y0i = (int)y0f;
            const float wx1 = ixf - x0f, wx0 = 1.0f - wx1;
            const float wy1 = iyf - y0f, wy0 = 1.0f - wy1;
            float s0 = 0.f, s1 = 0.f;
            #pragma unroll
            for (int cy = 0; cy < 2; ++cy) {
                const int yy = y0i + cy;
                const float wy = cy ? wy1 : wy0;
                if (yy >= 0 && yy < HH) {
                    #pragma unroll
                    for (int cx = 0; cx < 2; ++cx) {
                        const int xx = x0 + cx;
                        if (xx >= 0 && xx < WW) {
                            const float wgt = wy * (cx ? wx1 : wx0);
                            const int idx = yy * WW + xx;
                            s0 = fmaf(wgt, v2b[idx], s0);
                            s1 = fmaf(wgt, v2b[HH * WW + idx], s1);
                        }
                    }
                }
            }
            fb0 = f0 + s0;
            fb1 = f1 + s1;
            wv  = __expf(-sqrtf(fmaf(fb0, fb0, fb1 * fb1)));
        }
        g_lds[0][ly][lx] = fb0;
        g_lds[1][ly][lx] = fb1;
        g_lds[2][ly][lx] = wv;
    }

    // ---- flow tile with halo 2 (zero pad == unfold padding) ----
    for (int i = tid; i < FT * FT; i += 256) {
        const int ly = i / FT, lx = i - ly * FT;
        const int y = by0 - 2 + ly, x = bx0 - 2 + lx;
        float f0 = 0.f, f1 = 0.f;
        if (y >= 0 && y < HH && x >= 0 && x < WW) {
            f0 = v0b[y * WW + x];
            f1 = v0b[HH * WW + y * WW + x];
        }
        f_lds[0][ly][lx] = f0;
        f_lds[1][ly][lx] = f1;
    }
    __syncthreads();

    // ---- per-pixel: conv3x3 -> relu -> h[32] ----
    float g[3][3][3];
    #pragma unroll
    for (int ic = 0; ic < 3; ++ic)
        #pragma unroll
        for (int ky = 0; ky < 3; ++ky)
            #pragma unroll
            for (int kx = 0; kx < 3; ++kx)
                g[ic][ky][kx] = g_lds[ic][ty + ky][tx + kx];

    float h[HID];
    #pragma unroll
    for (int oc = 0; oc < HID; ++oc) {
        float acc = b1[oc];
        #pragma unroll
        for (int ic = 0; ic < 3; ++ic)
            #pragma unroll
            for (int ky = 0; ky < 3; ++ky)
                #pragma unroll
                for (int kx = 0; kx < 3; ++kx)
                    acc = fmaf(w1[((oc * 3 + ic) * 3 + ky) * 3 + kx],
                               g[ic][ky][kx], acc);
        h[oc] = fmaxf(acc, 0.0f);
    }

    // ---- dynamic kernels (1x1 conv) fused with patch combine ----
    float r0 = 0.f, r1 = 0.f;
    for (int k = 0; k < KK; ++k) {
        const int kyy = k / 5, kxx = k - kyy * 5;
        const float p0 = f_lds[0][ty + kyy][tx + kxx];
        const float p1 = f_lds[1][ty + kyy][tx + kxx];
        float k0a = 0.f, k0b = 0.f, k1a = 0.f, k1b = 0.f;
        #pragma unroll
        for (int j = 0; j < 16; ++j) {
            k0a = fmaf(w2[k * HID + j],             h[j],      k0a);
            k0b = fmaf(w2[k * HID + 16 + j],        h[16 + j], k0b);
            k1a = fmaf(w2[(KK + k) * HID + j],      h[j],      k1a);
            k1b = fmaf(w2[(KK + k) * HID + 16 + j], h[16 + j], k1b);
        }
        r0 = fmaf(b2[k]      + k0a + k0b, p0, r0);
        r1 = fmaf(b2[KK + k] + k1a + k1b, p1, r1);
    }

    const int y = by0 + ty, x = bx0 + tx;
    out[(size_t)(b * 2 + 0) * HH * WW + y * WW + x] = r0;
    out[(size_t)(b * 2 + 1) * HH * WW + y * WW + x] = r1;
}

extern "C" void kernel_launch(void* const* d_in, const int* in_sizes, int n_in,
                              void* d_out, int out_size, void* d_ws, size_t ws_size,
                              hipStream_t stream) {
    const float* v0 = (const float*)d_in[0];
    const float* v2 = (const float*)d_in[1];
    const float* w1 = (const float*)d_in[2];
    const float* b1 = (const float*)d_in[3];
    const float* w2 = (const float*)d_in[4];
    const float* b2 = (const float*)d_in[5];
    float* out = (float*)d_out;

    dim3 block(TS, TS, 1);
    dim3 grid(WW / TS, HH / TS, BB);
    temporal_refine_kernel<<<grid, block, 0, stream>>>(v0, v2, w1, b1, w2, b2, out);
}